// Round 7
// baseline (466.966 us; speedup 1.0000x reference)
//
#include <hip/hip_runtime.h>
#include <hip/hip_bf16.h>

#define B_TOT 131072
#define D     32
#define H1    50
#define QF    528     // tril feature count
#define H2    700
#define KP    544     // quad K padded to 17*32 (W2aT row stride)
#define QSTR  548     // quadls LDS row stride (ushorts)
#define NPH   768     // H2 padded to 16 waves * 48
#define MROWS 32      // batch rows per block
#define W2B_STRIDE 800

typedef __attribute__((ext_vector_type(8))) short  short8x;
typedef __attribute__((ext_vector_type(4))) float  floatx4;

static __device__ __forceinline__ unsigned short f2bf(float f) {
    __hip_bfloat16 h = __float2bfloat16(f);   // RNE
    return __builtin_bit_cast(unsigned short, h);
}

static __device__ __forceinline__ float tanh_fast(float x) {
    float xc = fminf(15.f, fmaxf(-15.f, x));
    float e  = __expf(2.f * xc);
    return 1.f - 2.f * __builtin_amdgcn_rcpf(e + 1.f);
}

// ---------------- prep: convert/pad weights into workspace ----------------
__global__ void prep_kernel(const float* __restrict__ W2a, const float* __restrict__ b2a,
                            const float* __restrict__ W2b,
                            unsigned short* __restrict__ W2aT,
                            unsigned short* __restrict__ W2bT,
                            float* __restrict__ b2ap) {
    int idx = blockIdx.x * 256 + threadIdx.x;
    const int N1 = NPH * KP;            // 417792
    const int N2 = 32 * W2B_STRIDE;     // 25600
    if (idx < N1) {
        int c = idx / KP, k = idx - c * KP;
        float v = (c < H2 && k < QF) ? W2a[k * H2 + c] : 0.f;
        W2aT[idx] = f2bf(v);
    } else if (idx < N1 + N2) {
        int j = idx - N1;
        int c = j / W2B_STRIDE, k = j - c * W2B_STRIDE;
        float v = (k < H2) ? W2b[k * D + c] : 0.f;
        W2bT[j] = f2bf(v);
    } else if (idx < N1 + N2 + NPH) {
        int k = idx - N1 - N2;
        b2ap[k] = (k < H2) ? b2a[k] : 0.f;
    }
}

// ---------------- fused main kernel ----------------
// Round-7: 32-row blocks, LDS 79.1 KB -> 2 resident blocks/CU (8 waves/SIMD,
// independent barrier domains). net1 moved fully into registers via __shfl
// (h1w LDS buffer eliminated). Live set halves (hacc[2][3], o2h[2][2]) to
// fit the 64-VGPR budget 8 waves/EU requires.
__global__ __launch_bounds__(1024, 8)
__attribute__((amdgpu_waves_per_eu(8, 8)))
void fused_kernel(
    const float* __restrict__ y,   const float* __restrict__ W1a,
    const float* __restrict__ b1a, const float* __restrict__ W1b,
    const float* __restrict__ b1b, const float* __restrict__ b2b,
    const unsigned short* __restrict__ W2aT, const unsigned short* __restrict__ W2bT,
    const float* __restrict__ b2ap, float* __restrict__ out) {

    __shared__ unsigned short quadls[MROWS][QSTR]; // 35072 B; reused post-K as f32 staging (32 KB)
    __shared__ float          yls[MROWS][36];      //  4608 B
    __shared__ float          outls[MROWS][36];    //  4608 B
    __shared__ unsigned short hst[16][16][68];     // 34816 B per-wave h re-stage
                                                   // total 79104 B <= 81920 (2 blocks/CU)

    const int tid  = threadIdx.x;
    const int lane = tid & 63;
    const int w    = tid >> 6;      // wave 0..15
    const int l15  = lane & 15;
    const int lg   = lane >> 4;     // 0..3
    const int row0 = blockIdx.x * MROWS;

    // ---- Phase A: load y tile; zero hst K-pad cols 48..63 ----
    if (tid < 256) {
        int r = tid >> 3, c = (tid & 7) * 4;
        floatx4 v = *reinterpret_cast<const floatx4*>(y + (row0 + r) * D + c);
        *reinterpret_cast<floatx4*>(&yls[r][c]) = v;
    }
    {   // 16 waves x (16 rows x 4 shorts) = all of [16][16][48..64)
        int rr = lane >> 2, cc0 = 48 + (lane & 3) * 4;
        *reinterpret_cast<unsigned long long*>(&hst[w][rr][cc0]) = 0ULL;
    }
    __syncthreads();

    // ---- Phase B: build quad (bf16): one (row,i) task per thread ----
    {
        int r = tid >> 5, i = tid & 31;
        int base = (i * (i + 1)) >> 1;
        float yi = yls[r][i];
        for (int j4 = 0; j4 <= i; j4 += 4) {
            floatx4 yv = *reinterpret_cast<const floatx4*>(&yls[r][j4]);
            #pragma unroll
            for (int jj = 0; jj < 4; ++jj) {
                int j = j4 + jj;
                if (j <= i) quadls[r][base + j] = f2bf(yi * yv[jj]);
            }
        }
    }
    if (tid < 512) quadls[tid >> 4][528 + (tid & 15)] = 0;  // K-pad 528..543
    __syncthreads();

    // ---- Main: wave w owns hidden cols [w*48, w*48+48), single K-pass ----
    const int hb = w * 48;
    floatx4 hacc[2][3];
    #pragma unroll
    for (int m = 0; m < 2; ++m)
        #pragma unroll
        for (int nf = 0; nf < 3; ++nf) hacc[m][nf] = (floatx4){0.f, 0.f, 0.f, 0.f};

    const unsigned short* bpt = W2aT + (hb + l15) * KP + lg * 8;

    #pragma unroll 4
    for (int k = 0; k < 17; ++k) {
        short8x a[2];
        #pragma unroll
        for (int m = 0; m < 2; ++m)
            a[m] = *reinterpret_cast<const short8x*>(&quadls[m * 16 + l15][k * 32 + lg * 8]);
        short8x bfr[3];
        #pragma unroll
        for (int nf = 0; nf < 3; ++nf)
            bfr[nf] = *reinterpret_cast<const short8x*>(bpt + nf * 16 * KP + k * 32);
        #pragma unroll
        for (int m = 0; m < 2; ++m)
            #pragma unroll
            for (int nf = 0; nf < 3; ++nf)
                hacc[m][nf] = __builtin_amdgcn_mfma_f32_16x16x32_bf16(a[m], bfr[nf], hacc[m][nf], 0, 0, 0);
    }

    // ---- epilogue: bias + tanh -> bf16 re-stage -> second GEMM (K=64) ----
    float bias[3];
    #pragma unroll
    for (int nf = 0; nf < 3; ++nf) bias[nf] = b2ap[hb + nf * 16 + l15];

    short8x bw[2][2];
    #pragma unroll
    for (int ks = 0; ks < 2; ++ks)
        #pragma unroll
        for (int of = 0; of < 2; ++of)
            bw[ks][of] = *reinterpret_cast<const short8x*>(
                W2bT + (of * 16 + l15) * W2B_STRIDE + hb + ks * 32 + lg * 8);

    floatx4 o2h[2][2];
    #pragma unroll
    for (int m = 0; m < 2; ++m)
        #pragma unroll
        for (int of = 0; of < 2; ++of) o2h[m][of] = (floatx4){0.f, 0.f, 0.f, 0.f};

    #pragma unroll
    for (int m = 0; m < 2; ++m) {
        #pragma unroll
        for (int nf = 0; nf < 3; ++nf)
            #pragma unroll
            for (int r = 0; r < 4; ++r)
                hst[w][lg * 4 + r][nf * 16 + l15] =
                    f2bf(tanh_fast(hacc[m][nf][r] + bias[nf]));
        short8x aa0 = *reinterpret_cast<const short8x*>(&hst[w][l15][lg * 8]);
        short8x aa1 = *reinterpret_cast<const short8x*>(&hst[w][l15][32 + lg * 8]);
        o2h[m][0] = __builtin_amdgcn_mfma_f32_16x16x32_bf16(aa0, bw[0][0], o2h[m][0], 0, 0, 0);
        o2h[m][1] = __builtin_amdgcn_mfma_f32_16x16x32_bf16(aa0, bw[0][1], o2h[m][1], 0, 0, 0);
        o2h[m][0] = __builtin_amdgcn_mfma_f32_16x16x32_bf16(aa1, bw[1][0], o2h[m][0], 0, 0, 0);
        o2h[m][1] = __builtin_amdgcn_mfma_f32_16x16x32_bf16(aa1, bw[1][1], o2h[m][1], 0, 0, 0);
    }

    // ---- net1, fully in registers: wave w owns rows w*2, w*2+1 ----
    {
        int myrow = lane >> 5;            // 0 or 1 (half-wave per row)
        int rowa  = w * 2 + myrow;
        int c     = lane & 31;            // output / hidden column
        float h1a, h1b = 0.f;
        {
            float acc = b1a[c];
            #pragma unroll
            for (int i = 0; i < D; ++i) acc += yls[rowa][i] * W1a[i * H1 + c];
            h1a = tanh_fast(acc);
        }
        if (c < H1 - 32) {
            float acc = b1a[32 + c];
            #pragma unroll
            for (int i = 0; i < D; ++i) acc += yls[rowa][i] * W1a[i * H1 + 32 + c];
            h1b = tanh_fast(acc);
        }
        float acc = b1b[c] + b2b[c];
        #pragma unroll
        for (int k = 0; k < 32; ++k) {
            float hv = __shfl(h1a, (lane & 32) + k);
            acc += hv * W1b[k * D + c];
        }
        #pragma unroll
        for (int k = 0; k < H1 - 32; ++k) {
            float hv = __shfl(h1b, (lane & 32) + k);
            acc += hv * W1b[(32 + k) * D + c];
        }
        outls[rowa][c] = acc;             // out1 + all biases
    }
    __syncthreads();   // all quadls K-reads done; outls initialized

    // ---- parallel staged reduce of o2h into outls (2 groups of 8 waves) ----
    float* stagef = (float*)&quadls[0][0];   // 8 panels * 1024 f32 = 32 KB
    const int rr = tid >> 5, rc = tid & 31;  // one output element per thread

    if (w >= 8) {
        int p = w - 8;
        #pragma unroll
        for (int m = 0; m < 2; ++m)
            #pragma unroll
            for (int of = 0; of < 2; ++of)
                #pragma unroll
                for (int r = 0; r < 4; ++r)
                    stagef[p * 1024 + (m * 16 + lg * 4 + r) * 32 + of * 16 + l15] = o2h[m][of][r];
    }
    __syncthreads();
    {
        float s = 0.f;
        #pragma unroll
        for (int p = 0; p < 8; ++p) s += stagef[p * 1024 + rr * 32 + rc];
        outls[rr][rc] += s;
    }
    __syncthreads();
    if (w < 8) {
        #pragma unroll
        for (int m = 0; m < 2; ++m)
            #pragma unroll
            for (int of = 0; of < 2; ++of)
                #pragma unroll
                for (int r = 0; r < 4; ++r)
                    stagef[w * 1024 + (m * 16 + lg * 4 + r) * 32 + of * 16 + l15] = o2h[m][of][r];
    }
    __syncthreads();
    {
        float s = 0.f;
        #pragma unroll
        for (int p = 0; p < 8; ++p) s += stagef[p * 1024 + rr * 32 + rc];
        outls[rr][rc] += s;
    }
    __syncthreads();

    // ---- write out ----
    if (tid < 256) {
        int r = tid >> 3, c = (tid & 7) * 4;
        floatx4 v = *reinterpret_cast<const floatx4*>(&outls[r][c]);
        *reinterpret_cast<floatx4*>(out + (row0 + r) * D + c) = v;
    }
}

extern "C" void kernel_launch(void* const* d_in, const int* in_sizes, int n_in,
                              void* d_out, int out_size, void* d_ws, size_t ws_size,
                              hipStream_t stream) {
    const float* y   = (const float*)d_in[1];
    const float* W1a = (const float*)d_in[2];
    const float* b1a = (const float*)d_in[3];
    const float* W1b = (const float*)d_in[4];
    const float* b1b = (const float*)d_in[5];
    const float* W2a = (const float*)d_in[6];
    const float* b2a = (const float*)d_in[7];
    const float* W2b = (const float*)d_in[8];
    const float* b2b = (const float*)d_in[9];

    unsigned short* W2aT = (unsigned short*)d_ws;                          // 835584 B
    unsigned short* W2bT = (unsigned short*)((char*)d_ws + 835584);        //  51200 B
    float*          b2ap = (float*)((char*)d_ws + 835584 + 51200);         //   3072 B

    const int prep_tasks = NPH * KP + 32 * W2B_STRIDE + NPH;               // 444160
    prep_kernel<<<(prep_tasks + 255) / 256, 256, 0, stream>>>(W2a, b2a, W2b, W2aT, W2bT, b2ap);
    fused_kernel<<<B_TOT / MROWS, 1024, 0, stream>>>(y, W1a, b1a, W1b, b1b, b2b,
                                                     W2aT, W2bT, b2ap, (float*)d_out);
}

// Round 8
// 211.495 us; speedup vs baseline: 2.2079x; 2.2079x over previous
//
#include <hip/hip_runtime.h>
#include <hip/hip_bf16.h>

#define B_TOT 131072
#define D     32
#define H1    50
#define QF    528      // tril feature count (k-row 528 = folded bias, 529..543 = 0)
#define H2    700
#define MROWS 32       // batch rows per block
#define QSTR  548      // quadls row stride (ushorts)

typedef __attribute__((ext_vector_type(8))) short  short8x;
typedef __attribute__((ext_vector_type(4))) float  floatx4;

static __device__ __forceinline__ unsigned short f2bf(float f) {
    __hip_bfloat16 h = __float2bfloat16(f);   // RNE
    return __builtin_bit_cast(unsigned short, h);
}
static __device__ __forceinline__ float bf2f(unsigned short u) {
    unsigned int x = (unsigned int)u << 16;
    return __builtin_bit_cast(float, x);
}
static __device__ __forceinline__ float tanh_fast(float x) {
    float xc = fminf(15.f, fmaxf(-15.f, x));
    float e  = __expf(2.f * xc);
    return 1.f - 2.f * __builtin_amdgcn_rcpf(e + 1.f);
}

// ---------------- prep: pre-fragmented bf16 weight layouts ----------------
// W2aT: [k=0..16][panel p=0..47][lane 0..63][j 0..7]  (417792 ushorts)
//   element = W2a[kk][c], kk = k*32+(lane>>4)*8+j, c = p*16+(lane&15)
//   kk==528 -> b2a[c]  (bias folded as extra K-row; quad k=528 is 1.0)
// W2bT: [wave w=0..15][ks=0..1][of=0..1][lane][j]     (32768 ushorts)
//   element = W2b[w*48 + ks*32+(lane>>4)*8+j][of*16+(lane&15)], 0 beyond 48/H2
__global__ void prep_kernel(const float* __restrict__ W2a, const float* __restrict__ b2a,
                            const float* __restrict__ W2b,
                            unsigned short* __restrict__ W2aT,
                            unsigned short* __restrict__ W2bT) {
    int idx = blockIdx.x * 256 + threadIdx.x;
    const int N1 = 17 * 48 * 512;    // 417792
    const int N2 = 16 * 4 * 512;     // 32768
    if (idx < N1) {
        int k   = idx / (48 * 512);
        int rem = idx - k * (48 * 512);
        int p   = rem >> 9;
        int q   = rem & 511;
        int ln  = q >> 3, j = q & 7;
        int kk  = k * 32 + ((ln >> 4) << 3) + j;
        int c   = (p << 4) + (ln & 15);
        float v = 0.f;
        if (c < H2) {
            if (kk < QF)       v = W2a[kk * H2 + c];
            else if (kk == QF) v = b2a[c];
        }
        W2aT[idx] = f2bf(v);
    } else if (idx < N1 + N2) {
        int i2 = idx - N1;
        int q  = i2 & 511;
        int ln = q >> 3, j = q & 7;
        int w  = i2 >> 11;
        int ks = (i2 >> 10) & 1;
        int of = (i2 >> 9) & 1;
        int kl = (ks << 5) + ((ln >> 4) << 3) + j;   // local k 0..63
        int kg = w * 48 + kl;
        int c  = (of << 4) + (ln & 15);
        float v = (kl < 48 && kg < H2) ? W2b[kg * D + c] : 0.f;
        W2bT[i2] = f2bf(v);
    }
}

// ---------------- fused main kernel ----------------
// Round-8: true <=64-VGPR design so waves_per_eu(8,8) doesn't spill:
//  - bias folded into GEMM1 K-row 528 (no bias regs)
//  - o2 transient per m-pass, staged as bf16 into quadls (dead post-K barrier)
//  - net1 result kept in ONE register (mapping == reduce mapping), outls gone
//  - SGPR-based fragment addressing (readfirstlane(w) + lane voffset + imm)
// LDS 74.5 KB -> 2 blocks/CU x 16 waves = 8 waves/SIMD, 2 barrier domains.
__global__ __launch_bounds__(1024, 8)
__attribute__((amdgpu_waves_per_eu(8, 8)))
void fused_kernel(
    const float* __restrict__ y,   const float* __restrict__ W1a,
    const float* __restrict__ b1a, const float* __restrict__ W1b,
    const float* __restrict__ b1b, const float* __restrict__ b2b,
    const unsigned short* __restrict__ W2aT, const unsigned short* __restrict__ W2bT,
    float* __restrict__ out) {

    __shared__ unsigned short quadls[MROWS][QSTR]; // 35072 B; post-K reused: bf16 stage [16][1024] (32768 B)
    __shared__ float          yls[MROWS][36];      //  4608 B
    __shared__ unsigned short hst[16][16][68];     // 34816 B per-wave re-stage   => total 74496 B

    const int tid  = threadIdx.x;
    const int lane = tid & 63;
    const int w    = tid >> 6;                         // wave 0..15
    const int wu   = __builtin_amdgcn_readfirstlane(w);
    const int l15  = lane & 15;
    const int lg   = lane >> 4;                        // 0..3
    const int row0 = blockIdx.x * MROWS;

    // ---- Phase A: y tile (1 float/thread, coalesced); zero hst K-pad (wave-local) ----
    yls[tid >> 5][tid & 31] = y[row0 * D + tid];
    {
        int rr = lane >> 2, cc0 = 48 + (lane & 3) * 4;
        *reinterpret_cast<unsigned long long*>(&hst[w][rr][cc0]) = 0ULL;
    }
    __syncthreads();

    // ---- Phase B: quad build (1 (row,i) task/thread) + bias-one + K-pad ----
    {
        int r = tid >> 5, i = tid & 31;
        int base = (i * (i + 1)) >> 1;
        float yi = yls[r][i];
        for (int j4 = 0; j4 <= i; j4 += 4) {
            floatx4 yv = *reinterpret_cast<const floatx4*>(&yls[r][j4]);
            #pragma unroll
            for (int jj = 0; jj < 4; ++jj) {
                int j = j4 + jj;
                if (j <= i) quadls[r][base + j] = f2bf(yi * yv[jj]);
            }
        }
    }
    if (tid < 512) {   // cols 528..543: 528 = 1.0 (bias row), rest 0
        int r = tid >> 4, c = 528 + (tid & 15);
        quadls[r][c] = (c == 528) ? (unsigned short)0x3F80 : (unsigned short)0;
    }
    __syncthreads();

    // ---- K-loop: wave w owns hidden cols [w*48, w*48+48) ----
    floatx4 hacc00 = {0,0,0,0}, hacc01 = {0,0,0,0}, hacc02 = {0,0,0,0};
    floatx4 hacc10 = {0,0,0,0}, hacc11 = {0,0,0,0}, hacc12 = {0,0,0,0};
    {
        const unsigned short* bp = W2aT + wu * 3 * 512 + lane * 8;
        #pragma unroll 1
        for (int k = 0; k < 17; ++k) {
            short8x a0 = *reinterpret_cast<const short8x*>(&quadls[l15][k * 32 + lg * 8]);
            short8x a1 = *reinterpret_cast<const short8x*>(&quadls[16 + l15][k * 32 + lg * 8]);
            short8x b0 = *reinterpret_cast<const short8x*>(bp);
            short8x b1 = *reinterpret_cast<const short8x*>(bp + 512);
            short8x b2 = *reinterpret_cast<const short8x*>(bp + 1024);
            hacc00 = __builtin_amdgcn_mfma_f32_16x16x32_bf16(a0, b0, hacc00, 0, 0, 0);
            hacc01 = __builtin_amdgcn_mfma_f32_16x16x32_bf16(a0, b1, hacc01, 0, 0, 0);
            hacc02 = __builtin_amdgcn_mfma_f32_16x16x32_bf16(a0, b2, hacc02, 0, 0, 0);
            hacc10 = __builtin_amdgcn_mfma_f32_16x16x32_bf16(a1, b0, hacc10, 0, 0, 0);
            hacc11 = __builtin_amdgcn_mfma_f32_16x16x32_bf16(a1, b1, hacc11, 0, 0, 0);
            hacc12 = __builtin_amdgcn_mfma_f32_16x16x32_bf16(a1, b2, hacc12, 0, 0, 0);
            bp += 48 * 512;
        }
    }
    __syncthreads();   // all quadls K-reads complete -> stage region is free

    // ---- epilogue: tanh -> hst -> GEMM2 (transient o2) -> bf16 stage ----
    unsigned short* stage = &quadls[0][0];             // [16 waves][32 rows][32 cols] bf16
    {
        const unsigned short* wb = W2bT + wu * 4 * 512 + lane * 8;
        #pragma unroll
        for (int m = 0; m < 2; ++m) {
            const floatx4 h0 = m ? hacc10 : hacc00;
            const floatx4 h1 = m ? hacc11 : hacc01;
            const floatx4 h2 = m ? hacc12 : hacc02;
            #pragma unroll
            for (int r = 0; r < 4; ++r) {
                hst[w][lg * 4 + r][l15]      = f2bf(tanh_fast(h0[r]));
                hst[w][lg * 4 + r][16 + l15] = f2bf(tanh_fast(h1[r]));
                hst[w][lg * 4 + r][32 + l15] = f2bf(tanh_fast(h2[r]));
            }
            short8x aa0 = *reinterpret_cast<const short8x*>(&hst[w][l15][lg * 8]);
            short8x aa1 = *reinterpret_cast<const short8x*>(&hst[w][l15][32 + lg * 8]);
            floatx4 o20 = {0,0,0,0}, o21 = {0,0,0,0};
            {
                short8x bw00 = *reinterpret_cast<const short8x*>(wb);
                short8x bw01 = *reinterpret_cast<const short8x*>(wb + 512);
                o20 = __builtin_amdgcn_mfma_f32_16x16x32_bf16(aa0, bw00, o20, 0, 0, 0);
                o21 = __builtin_amdgcn_mfma_f32_16x16x32_bf16(aa0, bw01, o21, 0, 0, 0);
            }
            {
                short8x bw10 = *reinterpret_cast<const short8x*>(wb + 1024);
                short8x bw11 = *reinterpret_cast<const short8x*>(wb + 1536);
                o20 = __builtin_amdgcn_mfma_f32_16x16x32_bf16(aa1, bw10, o20, 0, 0, 0);
                o21 = __builtin_amdgcn_mfma_f32_16x16x32_bf16(aa1, bw11, o21, 0, 0, 0);
            }
            #pragma unroll
            for (int r = 0; r < 4; ++r) {
                int row = m * 16 + lg * 4 + r;
                stage[w * 1024 + row * 32 + l15]      = f2bf(o20[r]);
                stage[w * 1024 + row * 32 + 16 + l15] = f2bf(o21[r]);
            }
        }
    }

    // ---- net1 in registers: wave w -> rows {w*2, w*2+1}, half-wave each ----
    float o1;
    {
        int rowa = (tid >> 5);            // == w*2 + (lane>>5)
        int c    = lane & 31;
        float h1a, h1b = 0.f;
        {
            float acc = b1a[c];
            #pragma unroll 8
            for (int i = 0; i < D; ++i) acc += yls[rowa][i] * W1a[i * H1 + c];
            h1a = tanh_fast(acc);
        }
        if (c < H1 - 32) {
            float acc = b1a[32 + c];
            #pragma unroll 8
            for (int i = 0; i < D; ++i) acc += yls[rowa][i] * W1a[i * H1 + 32 + c];
            h1b = tanh_fast(acc);
        }
        o1 = b1b[c] + b2b[c];
        #pragma unroll 8
        for (int k = 0; k < 32; ++k) {
            float hv = __shfl(h1a, (lane & 32) + k);
            o1 += hv * W1b[k * D + c];
        }
        #pragma unroll 6
        for (int k = 0; k < H1 - 32; ++k) {
            float hv = __shfl(h1b, (lane & 32) + k);
            o1 += hv * W1b[(32 + k) * D + c];
        }
    }
    __syncthreads();   // all stage writes visible

    // ---- reduce 16 bf16 panels + out1, write (thread t -> flat elem t) ----
    {
        float s = o1;
        #pragma unroll
        for (int p = 0; p < 16; ++p)
            s += bf2f(stage[p * 1024 + tid]);
        out[row0 * D + tid] = s;
    }
}

extern "C" void kernel_launch(void* const* d_in, const int* in_sizes, int n_in,
                              void* d_out, int out_size, void* d_ws, size_t ws_size,
                              hipStream_t stream) {
    const float* y   = (const float*)d_in[1];
    const float* W1a = (const float*)d_in[2];
    const float* b1a = (const float*)d_in[3];
    const float* W1b = (const float*)d_in[4];
    const float* b1b = (const float*)d_in[5];
    const float* W2a = (const float*)d_in[6];
    const float* b2a = (const float*)d_in[7];
    const float* W2b = (const float*)d_in[8];
    const float* b2b = (const float*)d_in[9];

    unsigned short* W2aT = (unsigned short*)d_ws;                      // 835584 B
    unsigned short* W2bT = (unsigned short*)((char*)d_ws + 835584);    //  65536 B

    const int prep_tasks = 17 * 48 * 512 + 16 * 4 * 512;               // 450560
    prep_kernel<<<(prep_tasks + 255) / 256, 256, 0, stream>>>(W2a, b2a, W2b, W2aT, W2bT);
    fused_kernel<<<B_TOT / MROWS, 1024, 0, stream>>>(y, W1a, b1a, W1b, b1b, b2b,
                                                     W2aT, W2bT, (float*)d_out);
}